// Round 4
// baseline (109.963 us; speedup 1.0000x reference)
//
#include <hip/hip_runtime.h>
#include <hip/hip_bf16.h>

typedef float f32x4 __attribute__((ext_vector_type(4)));
typedef short s16x8 __attribute__((ext_vector_type(8)));
typedef short s16x4 __attribute__((ext_vector_type(4)));

#define N_NODES 768
#define NODE_DIM_ 256
#define HDIM 64
#define EDIM 128
#define CTILES 48                       // 768 / 16
#define TILES_TOTAL (N_NODES * CTILES)  // 36864

static __device__ __forceinline__ short f2bf(float f) {
    __hip_bfloat16 h = __float2bfloat16(f);
    return __builtin_bit_cast(short, h);
}

// ---------- Kernel 0: W1g = g*W1 (row-scaled), S1 = colsum(W1g), C1 = b@W1 + b1 ----------
__global__ void prep_kernel(const float* __restrict__ W1, const float* __restrict__ b1,
                            const float* __restrict__ lng, const float* __restrict__ lnb,
                            float* __restrict__ W1g, float* __restrict__ S1,
                            float* __restrict__ C1) {
    int n = threadIdx.x;  // 64 threads
    float s = 0.f, c = 0.f;
#pragma unroll 8
    for (int k = 0; k < HDIM; ++k) {
        float w  = W1[k * HDIM + n];
        float wg = lng[k] * w;
        W1g[k * HDIM + n] = wg;
        s += wg;
        c = fmaf(lnb[k], w, c);
    }
    S1[n] = s;
    C1[n] = c + b1[n];
}

// ---------- Kernel 1: projections + per-row stats + P = N @ W1g ----------
__global__ __launch_bounds__(256) void proj_kernel(
        const float* __restrict__ x,
        const float* __restrict__ Wi, const float* __restrict__ bi,
        const float* __restrict__ Wj, const float* __restrict__ bj,
        const float* __restrict__ W1g,
        __hip_bfloat16* __restrict__ NIbf, __hip_bfloat16* __restrict__ NJbf,
        float* __restrict__ Pi, float* __restrict__ Pj,
        float* __restrict__ mi, float* __restrict__ qi,
        float* __restrict__ mj, float* __restrict__ qj) {
    __shared__ float W1gL[HDIM * HDIM];   // 16 KB
    __shared__ float rowi[4][HDIM], rowj[4][HDIM];
    for (int idx = threadIdx.x; idx < HDIM * HDIM; idx += 256) W1gL[idx] = W1g[idx];

    int wave = threadIdx.x >> 6, lane = threadIdx.x & 63;
    int row  = blockIdx.x * 4 + wave;
    float ai = bi[lane], aj = bj[lane];
    const float* xr = x + row * NODE_DIM_;
#pragma unroll 8
    for (int k = 0; k < NODE_DIM_; ++k) {
        float xv = xr[k];
        ai = fmaf(xv, Wi[k * HDIM + lane], ai);
        aj = fmaf(xv, Wj[k * HDIM + lane], aj);
    }
    NIbf[row * HDIM + lane] = __float2bfloat16(ai);
    NJbf[row * HDIM + lane] = __float2bfloat16(aj);
    rowi[wave][lane] = ai;
    rowj[wave][lane] = aj;

    float si = ai, sqi = ai * ai, sj = aj, sqj = aj * aj;
#pragma unroll
    for (int o = 1; o < 64; o <<= 1) {
        si  += __shfl_xor(si, o);   sqi += __shfl_xor(sqi, o);
        sj  += __shfl_xor(sj, o);   sqj += __shfl_xor(sqj, o);
    }
    if (lane == 0) {
        mi[row] = si * (1.f / 64.f);  qi[row] = sqi * (1.f / 64.f);
        mj[row] = sj * (1.f / 64.f);  qj[row] = sqj * (1.f / 64.f);
    }
    __syncthreads();  // W1gL + row buffers ready

    float pi = 0.f, pj = 0.f;
#pragma unroll 8
    for (int k = 0; k < HDIM; ++k) {
        float wg = W1gL[k * HDIM + lane];
        pi = fmaf(rowi[wave][k], wg, pi);
        pj = fmaf(rowj[wave][k], wg, pj);
    }
    Pi[row * HDIM + lane] = pi;
    Pj[row * HDIM + lane] = pj;
}

// ---------- Kernel 2: G[a][c] = dot(n_i[c], n_j[a])  (768x768, bf16 MFMA) ----------
__global__ __launch_bounds__(256) void gdot_kernel(
        const __hip_bfloat16* __restrict__ NIbf,
        const __hip_bfloat16* __restrict__ NJbf,
        float* __restrict__ G) {
    int wave = threadIdx.x >> 6, lane = threadIdx.x & 63;
    int l15 = lane & 15, hi = lane >> 4;
    int tile = blockIdx.x * 4 + wave;           // 48*48 = 2304 tiles
    int ta = tile / CTILES, tc = tile % CTILES;
    int a0 = ta * 16, c0 = tc * 16;

    const short* NJ = (const short*)NJbf;
    const short* NI = (const short*)NIbf;
    s16x8 a0f = *(const s16x8*)&NJ[(a0 + l15) * HDIM + hi * 8];
    s16x8 a1f = *(const s16x8*)&NJ[(a0 + l15) * HDIM + 32 + hi * 8];
    s16x8 b0f = *(const s16x8*)&NI[(c0 + l15) * HDIM + hi * 8];
    s16x8 b1f = *(const s16x8*)&NI[(c0 + l15) * HDIM + 32 + hi * 8];
    f32x4 acc = {0.f, 0.f, 0.f, 0.f};
    acc = __builtin_amdgcn_mfma_f32_16x16x32_bf16(a0f, b0f, acc, 0, 0, 0);
    acc = __builtin_amdgcn_mfma_f32_16x16x32_bf16(a1f, b1f, acc, 0, 0, 0);
    // D: col=l15 -> c, row=hi*4+r -> a
#pragma unroll
    for (int r = 0; r < 4; ++r)
        G[(size_t)(a0 + hi * 4 + r) * N_NODES + c0 + l15] = acc[r];
}

// ---------- Kernel 3: per-pair t = relu(rstd*(U - mu*S1) + C1); out = t@W2 + b2 ----------
__global__ __launch_bounds__(256) void edge2_kernel(
        const float* __restrict__ Pi, const float* __restrict__ Pj,
        const float* __restrict__ mi, const float* __restrict__ qi,
        const float* __restrict__ mj, const float* __restrict__ qj,
        const float* __restrict__ G,
        const float* __restrict__ S1, const float* __restrict__ C1,
        const float* __restrict__ W2, const float* __restrict__ b2,
        float* __restrict__ out) {
    __shared__ short W2L[8192];  // [(k>>3)][e(128)][k&7] bf16
    for (int idx = threadIdx.x; idx < 8192; idx += 256) {
        int k = idx >> 7, e = idx & 127;
        W2L[(k >> 3) * 1024 + e * 8 + (k & 7)] = f2bf(W2[idx]);
    }
    __syncthreads();

    const int wave = threadIdx.x >> 6;
    const int lane = threadIdx.x & 63;
    const int l15  = lane & 15;
    const int hi   = lane >> 4;

    // loop-invariant per-lane constants
    f32x4 S1a = *(const f32x4*)&S1[hi * 8];
    f32x4 S1b = *(const f32x4*)&S1[hi * 8 + 4];
    f32x4 S1c = *(const f32x4*)&S1[32 + hi * 8];
    f32x4 S1d = *(const f32x4*)&S1[32 + hi * 8 + 4];
    f32x4 C1a = *(const f32x4*)&C1[hi * 8];
    f32x4 C1b = *(const f32x4*)&C1[hi * 8 + 4];
    f32x4 C1c = *(const f32x4*)&C1[32 + hi * 8];
    f32x4 C1d = *(const f32x4*)&C1[32 + hi * 8 + 4];
    f32x4 b2v[8];
#pragma unroll
    for (int nt = 0; nt < 8; ++nt)
        b2v[nt] = *(const f32x4*)&b2[nt * 16 + hi * 4];

    const int wid = blockIdx.x * 4 + wave;
    const int nw  = gridDim.x * 4;
    for (int t = wid; t < TILES_TOTAL; t += nw) {
        int a  = t / CTILES;
        int c0 = (t - a * CTILES) * 16;
        int c  = c0 + l15;

        float mu   = mi[c] + mj[a];
        float ms   = qi[c] + qj[a] + G[(size_t)a * N_NODES + c] * (1.f / 32.f);
        float var  = ms - mu * mu;
        float rstd = rsqrtf(var + 1e-5f);
        float rm   = rstd * mu;

        const float* pic = Pi + c * HDIM;
        const float* pja = Pj + a * HDIM;
        f32x4 pi0 = *(const f32x4*)(pic + hi * 8);
        f32x4 pi1 = *(const f32x4*)(pic + hi * 8 + 4);
        f32x4 pi2 = *(const f32x4*)(pic + 32 + hi * 8);
        f32x4 pi3 = *(const f32x4*)(pic + 32 + hi * 8 + 4);
        f32x4 pj0 = *(const f32x4*)(pja + hi * 8);
        f32x4 pj1 = *(const f32x4*)(pja + hi * 8 + 4);
        f32x4 pj2 = *(const f32x4*)(pja + 32 + hi * 8);
        f32x4 pj3 = *(const f32x4*)(pja + 32 + hi * 8 + 4);

        s16x8 tf0, tf1;
#pragma unroll
        for (int j = 0; j < 4; ++j) {
            float t0 = fmaf(rstd, pi0[j] + pj0[j], fmaf(-rm, S1a[j], C1a[j]));
            float t1 = fmaf(rstd, pi1[j] + pj1[j], fmaf(-rm, S1b[j], C1b[j]));
            float t2 = fmaf(rstd, pi2[j] + pj2[j], fmaf(-rm, S1c[j], C1c[j]));
            float t3 = fmaf(rstd, pi3[j] + pj3[j], fmaf(-rm, S1d[j], C1d[j]));
            tf0[j]     = f2bf(fmaxf(t0, 0.f));
            tf0[4 + j] = f2bf(fmaxf(t1, 0.f));
            tf1[j]     = f2bf(fmaxf(t2, 0.f));
            tf1[4 + j] = f2bf(fmaxf(t3, 0.f));
        }

        // GEMM2 (swapped): lane -> out[c][e = nt*16 + hi*4 + r], dwordx4 stores
        float* op = out + ((size_t)(a * N_NODES + c)) * EDIM + hi * 4;
#pragma unroll
        for (int nt = 0; nt < 8; ++nt) {
            f32x4 acc = {0.f, 0.f, 0.f, 0.f};
            s16x8 w0 = *(const s16x8*)&W2L[(0 + hi) * 1024 + (nt * 16 + l15) * 8];
            s16x8 w1 = *(const s16x8*)&W2L[(4 + hi) * 1024 + (nt * 16 + l15) * 8];
            acc = __builtin_amdgcn_mfma_f32_16x16x32_bf16(w0, tf0, acc, 0, 0, 0);
            acc = __builtin_amdgcn_mfma_f32_16x16x32_bf16(w1, tf1, acc, 0, 0, 0);
            *(f32x4*)(op + nt * 16) = acc + b2v[nt];
        }
    }
}

// ================= fallback path (R3): used only if ws_size is too small =================
__global__ __launch_bounds__(256) void proj_fb_kernel(
        const float* __restrict__ x,
        const float* __restrict__ Wi, const float* __restrict__ bi,
        const float* __restrict__ Wj, const float* __restrict__ bj,
        float* __restrict__ NI, float* __restrict__ NJ) {
    int row  = blockIdx.x * 4 + (threadIdx.x >> 6);
    int lane = threadIdx.x & 63;
    float ai = bi[lane];
    float aj = bj[lane];
    const float* xr = x + row * NODE_DIM_;
#pragma unroll 8
    for (int k = 0; k < NODE_DIM_; ++k) {
        float xv = xr[k];
        ai = fmaf(xv, Wi[k * HDIM + lane], ai);
        aj = fmaf(xv, Wj[k * HDIM + lane], aj);
    }
    NI[row * HDIM + lane] = ai;
    NJ[row * HDIM + lane] = aj;
}

__global__ __launch_bounds__(256) void edge_fb_kernel(
        const float* __restrict__ NI, const float* __restrict__ NJ,
        const float* __restrict__ lng, const float* __restrict__ lnb,
        const float* __restrict__ W1, const float* __restrict__ b1,
        const float* __restrict__ W2, const float* __restrict__ b2,
        float* __restrict__ out) {
    __shared__ short W1L[4096];
    __shared__ short W2L[8192];
    __shared__ short TL[4][1024];
    for (int idx = threadIdx.x; idx < 4096; idx += 256) {
        int k = idx >> 6, n = idx & 63;
        W1L[(k >> 3) * 512 + n * 8 + (k & 7)] = f2bf(W1[idx]);
    }
    for (int idx = threadIdx.x; idx < 8192; idx += 256) {
        int k = idx >> 7, n = idx & 127;
        W2L[(k >> 3) * 1024 + n * 8 + (k & 7)] = f2bf(W2[idx]);
    }
    __syncthreads();
    const int wave = threadIdx.x >> 6;
    const int lane = threadIdx.x & 63;
    const int l15  = lane & 15;
    const int hi   = lane >> 4;
    const int swz  = (l15 & 7) << 4;
    float gl[8], gh[8], bl[8], bh[8];
#pragma unroll
    for (int j = 0; j < 8; ++j) {
        gl[j] = lng[hi * 8 + j];      gh[j] = lng[32 + hi * 8 + j];
        bl[j] = lnb[hi * 8 + j];      bh[j] = lnb[32 + hi * 8 + j];
    }
    float b1v[16];
#pragma unroll
    for (int nt = 0; nt < 4; ++nt)
#pragma unroll
        for (int r = 0; r < 4; ++r)
            b1v[nt * 4 + r] = b1[nt * 16 + hi * 4 + r];
    f32x4 b2v[8];
#pragma unroll
    for (int nt = 0; nt < 8; ++nt)
        b2v[nt] = *(const f32x4*)&b2[nt * 16 + hi * 4];
    char* tl = (char*)&TL[wave][0];
    const int wid = blockIdx.x * 4 + wave;
    const int nw  = gridDim.x * 4;
    for (int t = wid; t < TILES_TOTAL; t += nw) {
        int a  = t / CTILES;
        int c0 = (t - a * CTILES) * 16;
        const float* nip = NI + (c0 + l15) * HDIM + hi * 8;
        const float* njp = NJ + a * HDIM + hi * 8;
        float v[16];
#pragma unroll
        for (int j = 0; j < 8; ++j) {
            v[j]     = nip[j]      + njp[j];
            v[8 + j] = nip[32 + j] + njp[32 + j];
        }
        float s = 0.f, ss = 0.f;
#pragma unroll
        for (int j = 0; j < 16; ++j) { s += v[j]; ss = fmaf(v[j], v[j], ss); }
        s += __shfl_xor(s, 16);  ss += __shfl_xor(ss, 16);
        s += __shfl_xor(s, 32);  ss += __shfl_xor(ss, 32);
        float mu   = s * (1.f / 64.f);
        float var  = ss * (1.f / 64.f) - mu * mu;
        float rstd = rsqrtf(var + 1e-5f);
        s16x8 hf0, hf1;
#pragma unroll
        for (int j = 0; j < 8; ++j) {
            hf0[j] = f2bf(fmaf((v[j]     - mu) * rstd, gl[j], bl[j]));
            hf1[j] = f2bf(fmaf((v[8 + j] - mu) * rstd, gh[j], bh[j]));
        }
#pragma unroll
        for (int nt = 0; nt < 4; ++nt) {
            f32x4 acc = {0.f, 0.f, 0.f, 0.f};
            s16x8 w0 = *(const s16x8*)&W1L[(0 + hi) * 512 + (nt * 16 + l15) * 8];
            s16x8 w1 = *(const s16x8*)&W1L[(4 + hi) * 512 + (nt * 16 + l15) * 8];
            acc = __builtin_amdgcn_mfma_f32_16x16x32_bf16(w0, hf0, acc, 0, 0, 0);
            acc = __builtin_amdgcn_mfma_f32_16x16x32_bf16(w1, hf1, acc, 0, 0, 0);
            s16x4 tv;
#pragma unroll
            for (int r = 0; r < 4; ++r)
                tv[r] = f2bf(fmaxf(acc[r] + b1v[nt * 4 + r], 0.f));
            int wb = (l15 * 128 + (nt * 16 + hi * 4) * 2) ^ swz;
            *(s16x4*)(tl + wb) = tv;
        }
        int rb0 = (l15 * 128 + hi * 16) ^ swz;
        int rb1 = (l15 * 128 + hi * 16 + 64) ^ swz;
        s16x8 tf0 = *(const s16x8*)(tl + rb0);
        s16x8 tf1 = *(const s16x8*)(tl + rb1);
        float* op = out + ((size_t)(a * N_NODES + c0 + l15)) * EDIM + hi * 4;
#pragma unroll
        for (int nt = 0; nt < 8; ++nt) {
            f32x4 acc = {0.f, 0.f, 0.f, 0.f};
            s16x8 w0 = *(const s16x8*)&W2L[(0 + hi) * 1024 + (nt * 16 + l15) * 8];
            s16x8 w1 = *(const s16x8*)&W2L[(4 + hi) * 1024 + (nt * 16 + l15) * 8];
            acc = __builtin_amdgcn_mfma_f32_16x16x32_bf16(w0, tf0, acc, 0, 0, 0);
            acc = __builtin_amdgcn_mfma_f32_16x16x32_bf16(w1, tf1, acc, 0, 0, 0);
            *(f32x4*)(op + nt * 16) = acc + b2v[nt];
        }
    }
}

extern "C" void kernel_launch(void* const* d_in, const int* in_sizes, int n_in,
                              void* d_out, int out_size, void* d_ws, size_t ws_size,
                              hipStream_t stream) {
    const float* x   = (const float*)d_in[0];
    const float* Wi  = (const float*)d_in[2];
    const float* bi  = (const float*)d_in[3];
    const float* Wj  = (const float*)d_in[4];
    const float* bj  = (const float*)d_in[5];
    const float* lng = (const float*)d_in[6];
    const float* lnb = (const float*)d_in[7];
    const float* W1  = (const float*)d_in[8];
    const float* b1  = (const float*)d_in[9];
    const float* W2  = (const float*)d_in[10];
    const float* b2  = (const float*)d_in[11];
    float* out = (float*)d_out;

    // workspace layout (floats)
    float* ws = (float*)d_ws;
    const size_t oW1g = 0;            // 4096
    const size_t oS1  = 4096;         // 64
    const size_t oC1  = 4160;         // 64
    const size_t oPi  = 4224;         // 49152
    const size_t oPj  = 53376;        // 49152
    const size_t oMi  = 102528;       // 768
    const size_t oQi  = 103296;       // 768
    const size_t oMj  = 104064;       // 768
    const size_t oQj  = 104832;       // 768
    const size_t oG   = 105600;       // 589824
    const size_t oNI  = 695424;       // 24576 floats (49152 bf16)
    const size_t oNJ  = 720000;       // 24576 floats
    const size_t needF = 744576;

    if (ws_size < needF * sizeof(float)) {
        // fallback: R3 path (needs only 393KB)
        float* NI = ws;
        float* NJ = NI + N_NODES * HDIM;
        proj_fb_kernel<<<N_NODES / 4, 256, 0, stream>>>(x, Wi, bi, Wj, bj, NI, NJ);
        edge_fb_kernel<<<2304, 256, 0, stream>>>(NI, NJ, lng, lnb, W1, b1, W2, b2, out);
        return;
    }

    float* W1g = ws + oW1g;
    float* S1  = ws + oS1;
    float* C1  = ws + oC1;
    float* Pi  = ws + oPi;
    float* Pj  = ws + oPj;
    float* mi  = ws + oMi;
    float* qi  = ws + oQi;
    float* mj  = ws + oMj;
    float* qj  = ws + oQj;
    float* G   = ws + oG;
    __hip_bfloat16* NIbf = (__hip_bfloat16*)(ws + oNI);
    __hip_bfloat16* NJbf = (__hip_bfloat16*)(ws + oNJ);

    prep_kernel<<<1, 64, 0, stream>>>(W1, b1, lng, lnb, W1g, S1, C1);
    proj_kernel<<<N_NODES / 4, 256, 0, stream>>>(x, Wi, bi, Wj, bj, W1g,
                                                 NIbf, NJbf, Pi, Pj, mi, qi, mj, qj);
    gdot_kernel<<<2304 / 4, 256, 0, stream>>>(NIbf, NJbf, G);
    edge2_kernel<<<2304, 256, 0, stream>>>(Pi, Pj, mi, qi, mj, qj, G, S1, C1, W2, b2, out);
}